// Round 4
// baseline (310.054 us; speedup 1.0000x reference)
//
#include <hip/hip_runtime.h>
#include <hip/hip_bf16.h>

// Problem constants (fixed by reference)
#define B_ 4
#define S_ 2048
#define D_ 1024
#define H_ 16
#define DK_ 64

typedef __attribute__((ext_vector_type(8))) short short8;
typedef __attribute__((ext_vector_type(4))) float floatx4;
typedef __attribute__((ext_vector_type(16))) float floatx16;
typedef __attribute__((ext_vector_type(4))) unsigned int uint4v;

// round-to-nearest-even f32 -> bf16 bits
static __device__ __forceinline__ unsigned short f2bf(float f) {
    unsigned int u = __float_as_uint(f);
    u += 0x7fffu + ((u >> 16) & 1u);
    return (unsigned short)(u >> 16);
}

// pack two f32 -> bf16x2 (round-nearest-ties-up, cheap; for P only)
static __device__ __forceinline__ unsigned int pack2bf_fast(float a, float b) {
    unsigned int ua = (__float_as_uint(a) + 0x8000u) >> 16;
    unsigned int ub = (__float_as_uint(b) + 0x8000u) & 0xffff0000u;
    return ua | ub;
}

// pack two f32 -> bf16x2 (RNE, for outputs)
static __device__ __forceinline__ unsigned int pack2bf(float a, float b) {
    return (unsigned int)f2bf(a) | ((unsigned int)f2bf(b) << 16);
}

// v_permlane32_swap_b32 a, b : lanes[32:63] of a  <->  lanes[0:31] of b
// (CDNA4 ISA: swaps rows 2-3 of vdst with rows 0-1 of src0). VALU pipe, no LDS.
#define PLSWAP(a, b) asm volatile("v_permlane32_swap_b32 %0, %1" : "+v"(a), "+v"(b))

// ---------------- fused cast kernel (x + 4 weights in one launch) ----------------
struct CastAll {
    const float* x;
    const float* w[4];
    unsigned short* xd;
    unsigned short* wd[4];
};

__global__ void cast_all_kernel(CastAll a) {
    int i = blockIdx.x * blockDim.x + threadIdx.x; // over float4 groups
    const float* s;
    unsigned short* d;
    int j;
    if (i < 2097152) { // x: 8M elems = 2M float4
        s = a.x; d = a.xd; j = i;
    } else {           // 4 weights: 256K float4 each
        int k = i - 2097152;
        int w = k >> 18;
        j = k & 262143;
        s = a.w[w]; d = a.wd[w];
    }
    float4 v = ((const float4*)s)[j];
    ushort4 o;
    o.x = f2bf(v.x); o.y = f2bf(v.y); o.z = f2bf(v.z); o.w = f2bf(v.w);
    ((ushort4*)d)[j] = o;
}

// ---------------- m97-style GEMM: C[m,n] = sum_k A[m,k] * W[n,k] ----------------
// A: [M,K] bf16 row-major; W: [N,K] bf16 row-major (torch weight layout [out,in]).
// 128x128 tile, BK=64, 256 threads (4 waves, 2x2 of 64x64), global_load_lds w=16.
// blockIdx.z selects among 3 weight/output pairs (Q/K/V in one launch).
// VT2: the z==2 output (V) is stored TRANSPOSED as Vt[(b*1024 + col)][s]
//      for the flash kernel's B-operand staging.
template <typename OutT, bool VT2>
__global__ __launch_bounds__(256) void gemm_bt(
    const unsigned short* __restrict__ A,
    const unsigned short* __restrict__ W0,
    const unsigned short* __restrict__ W1,
    const unsigned short* __restrict__ W2,
    OutT* __restrict__ C0, OutT* __restrict__ C1, OutT* __restrict__ C2,
    int M, int N, int K)
{
    __shared__ __align__(16) unsigned short At[128 * 64]; // [row][k] k-contiguous, NO pad (global_load_lds)
    __shared__ __align__(16) unsigned short Bt[128 * 64];

    const unsigned short* W = (blockIdx.z == 0) ? W0 : ((blockIdx.z == 1) ? W1 : W2);
    OutT* C = (blockIdx.z == 0) ? C0 : ((blockIdx.z == 1) ? C1 : C2);

    const int n0 = blockIdx.x * 128;
    const int m0 = blockIdx.y * 128;
    const int wv = threadIdx.x >> 6;
    const int ln = threadIdx.x & 63;
    const int quad = ln >> 4;
    const int l15 = ln & 15;
    const int wm = (wv >> 1) * 64; // wave's 64x64 quadrant
    const int wn = (wv & 1) * 64;

    floatx4 acc[4][4];
#pragma unroll
    for (int i = 0; i < 4; i++)
#pragma unroll
        for (int j = 0; j < 4; j++) acc[i][j] = floatx4{0.f, 0.f, 0.f, 0.f};

    const int lr = ln >> 3;       // lane row within 8-row/1KB chunk
    const int lc = (ln & 7) * 8;  // lane col (elements)

    for (int k0 = 0; k0 < K; k0 += 64) {
        __syncthreads(); // prior iter's LDS reads done before overwrite
#pragma unroll
        for (int c = 0; c < 4; c++) {
            int rowA = wv * 32 + c * 8;
            const unsigned short* gA = A + (size_t)(m0 + rowA + lr) * K + k0 + lc;
            __builtin_amdgcn_global_load_lds(
                (const __attribute__((address_space(1))) void*)gA,
                (__attribute__((address_space(3))) void*)&At[rowA * 64], 16, 0, 0);
            const unsigned short* gB = W + (size_t)(n0 + rowA + lr) * K + k0 + lc;
            __builtin_amdgcn_global_load_lds(
                (const __attribute__((address_space(1))) void*)gB,
                (__attribute__((address_space(3))) void*)&Bt[rowA * 64], 16, 0, 0);
        }
        __syncthreads(); // drains vmcnt (compiler emits waitcnt before barrier)

#pragma unroll
        for (int kk = 0; kk < 2; kk++) {
            short8 af[4], bf[4];
#pragma unroll
            for (int i = 0; i < 4; i++)
                af[i] = *(const short8*)&At[(wm + i * 16 + l15) * 64 + kk * 32 + quad * 8];
#pragma unroll
            for (int j = 0; j < 4; j++)
                bf[j] = *(const short8*)&Bt[(wn + j * 16 + l15) * 64 + kk * 32 + quad * 8];
#pragma unroll
            for (int i = 0; i < 4; i++)
#pragma unroll
                for (int j = 0; j < 4; j++)
                    acc[i][j] = __builtin_amdgcn_mfma_f32_16x16x32_bf16(af[i], bf[j], acc[i][j], 0, 0, 0);
        }
    }

    if constexpr (VT2) {
        if (blockIdx.z == 2) {
            // transposed V store: Vt[(b*1024 + col)*2048 + s], 4 consec s -> b64
            unsigned short* Vt = (unsigned short*)C;
#pragma unroll
            for (int i = 0; i < 4; i++)
#pragma unroll
                for (int j = 0; j < 4; j++) {
                    int col = n0 + wn + j * 16 + l15;
                    int row0 = m0 + wm + i * 16 + quad * 4; // global s-row base, %4==0
                    int bb = row0 >> 11, ss = row0 & 2047;
                    size_t addr = ((size_t)(bb * 1024 + col)) * 2048 + ss;
                    uint2 pk;
                    pk.x = pack2bf(acc[i][j][0], acc[i][j][1]);
                    pk.y = pack2bf(acc[i][j][2], acc[i][j][3]);
                    *(uint2*)((unsigned short*)Vt + addr) = pk;
                }
            return;
        }
    }

    // epilogue: C/D layout row=quad*4+r, col=l15
#pragma unroll
    for (int i = 0; i < 4; i++)
#pragma unroll
        for (int j = 0; j < 4; j++)
#pragma unroll
            for (int r = 0; r < 4; r++) {
                int row = m0 + wm + i * 16 + quad * 4 + r;
                int col = n0 + wn + j * 16 + l15;
                float v = acc[i][j][r];
                if constexpr (sizeof(OutT) == 2)
                    C[(size_t)row * N + col] = (OutT)f2bf(v);
                else
                    C[(size_t)row * N + col] = v;
            }
}

// ---------------- flash attention (v4: permlane P-transpose, no P LDS) ----------------
// Q,K,O: [B*S, D] bf16 (head h at cols h*64..+63); Vt: [B*H*DK, S] bf16.
// Block: 256 thr = 4 waves; wave = 32 q-rows; block = 128 q; BK=64 keys/iter.
// S^T = K Q^T; P exits with lane(q=l31,half) holding key runs mt*32+8g+4*half+{0..3}.
// One v_permlane32_swap_b32 per dword pair rearranges the runs into the exact
// PV B-operand fragment {E.x,E.y,Od.x,Od.y} — zero LDS traffic for P.
__global__ __launch_bounds__(256, 4) void flash_attn(
    const unsigned short* __restrict__ Q,
    const unsigned short* __restrict__ K,
    const unsigned short* __restrict__ Vt,
    unsigned short* __restrict__ O)
{
    __shared__ __align__(16) unsigned short Kt[64 * 72]; // [key][dk], +8 pad
    __shared__ __align__(16) unsigned short VT[64 * 72]; // [dk][key], +8 pad

    const int qt = blockIdx.x;
    const int h = blockIdx.y;
    const int b = blockIdx.z;
    const int tid = threadIdx.x;
    const int wv = tid >> 6;
    const int ln = tid & 63;
    const int l31 = ln & 31;
    const int half = ln >> 5;

    const size_t base = ((size_t)b * S_) * D_ + (size_t)h * DK_; // Q,K,O
    const size_t vtbase = ((size_t)(b * 1024 + h * 64)) * (size_t)S_;

    // Q B-fragments (lane n=q reads its own row, k-contig), persist all iters
    const int qrow = qt * 128 + wv * 32 + l31;
    short8 qf[4];
    {
        const unsigned short* qp = Q + base + (size_t)qrow * D_ + half * 8;
#pragma unroll
        for (int ks = 0; ks < 4; ks++) qf[ks] = *(const short8*)(qp + ks * 16);
    }

    floatx16 Oacc[2];
#pragma unroll
    for (int mt = 0; mt < 2; mt++)
#pragma unroll
        for (int e = 0; e < 16; e++) Oacc[mt][e] = 0.f;
    float l_i = 0.f;

    // staging: 8 lanes cover one 64-elem row (coalesced 128B)
    const int srow = tid >> 3;      // row 0..31 (+32)
    const int scol = (tid & 7) * 8; // col chunk

    const float scl = 1.4426950408889634f / 8.0f; // log2(e)/sqrt(DK)
    const float CL = 12.0f; // fixed softmax reference (log2 domain)

    for (int kt = 0; kt < S_ / 64; kt++) {
        __syncthreads(); // all waves done reading Kt/VT of prev iter
#pragma unroll
        for (int c = 0; c < 2; c++) {
            int row = srow + c * 32;
            *(short8*)&Kt[row * 72 + scol] =
                *(const short8*)(K + base + (size_t)(kt * 64 + row) * D_ + scol);
            *(short8*)&VT[row * 72 + scol] =
                *(const short8*)(Vt + vtbase + (size_t)row * S_ + kt * 64 + scol);
        }
        __syncthreads();

        // S^T = K Q^T : A=Kt[m=key][k=dk], B=Q regs[n=q]; D col=q, row=key
        floatx16 sac[2];
#pragma unroll
        for (int mt = 0; mt < 2; mt++) {
#pragma unroll
            for (int e = 0; e < 16; e++) sac[mt][e] = 0.f;
#pragma unroll
            for (int ks = 0; ks < 4; ks++) {
                short8 kf = *(const short8*)&Kt[(mt * 32 + l31) * 72 + ks * 16 + half * 8];
                sac[mt] = __builtin_amdgcn_mfma_f32_32x32x16_bf16(kf, qf[ks], sac[mt], 0, 0, 0);
            }
        }

        // softmax: p = 2^(s*scl - CL); lane owns q=l31, key runs of 4 -> bf16x2 pairs
        uint2 run[2][4]; // [mt][g], keys mt*32 + 8g + 4*half + {0..3}
#pragma unroll
        for (int mt = 0; mt < 2; mt++)
#pragma unroll
            for (int g = 0; g < 4; g++) {
                float p0 = __builtin_amdgcn_exp2f(fmaf(sac[mt][4 * g + 0], scl, -CL));
                float p1 = __builtin_amdgcn_exp2f(fmaf(sac[mt][4 * g + 1], scl, -CL));
                float p2 = __builtin_amdgcn_exp2f(fmaf(sac[mt][4 * g + 2], scl, -CL));
                float p3 = __builtin_amdgcn_exp2f(fmaf(sac[mt][4 * g + 3], scl, -CL));
                l_i += (p0 + p1) + (p2 + p3);
                run[mt][g].x = pack2bf_fast(p0, p1);
                run[mt][g].y = pack2bf_fast(p2, p3);
            }

        // rearrange runs into B-fragments: swap hi-lanes of even-g run with
        // lo-lanes of odd-g run; fragment = {E.x, E.y, Od.x, Od.y} on all lanes
#pragma unroll
        for (int mt = 0; mt < 2; mt++)
#pragma unroll
            for (int t = 0; t < 2; t++) {
                PLSWAP(run[mt][2 * t].x, run[mt][2 * t + 1].x);
                PLSWAP(run[mt][2 * t].y, run[mt][2 * t + 1].y);
            }

        // O^T = V^T P^T : A=VT[m=dk][k=key], B=P frags (n=q, keys ks*16..+15)
#pragma unroll
        for (int mt2 = 0; mt2 < 2; mt2++)
#pragma unroll
            for (int t = 0; t < 2; t++) {
                int ks = mt2 * 2 + t;
                uint4v u = {run[mt2][2 * t].x, run[mt2][2 * t].y,
                            run[mt2][2 * t + 1].x, run[mt2][2 * t + 1].y};
                short8 pf = __builtin_bit_cast(short8, u);
#pragma unroll
                for (int mt = 0; mt < 2; mt++) {
                    short8 vf = *(const short8*)&VT[(mt * 32 + l31) * 72 + ks * 16 + half * 8];
                    Oacc[mt] = __builtin_amdgcn_mfma_f32_32x32x16_bf16(vf, pf, Oacc[mt], 0, 0, 0);
                }
            }
    }

    // l: lane's partial covers its 32 keys/iter; lanes (l, l+32) share q
    l_i += __shfl_xor(l_i, 32);
    float inv = 1.0f / l_i;

    // epilogue: lane owns q=qrow; dk = mt*32 + 8g + 4*half + r, runs of 4 -> b64
#pragma unroll
    for (int mt = 0; mt < 2; mt++)
#pragma unroll
        for (int g = 0; g < 4; g++) {
            uint2 pk;
            pk.x = pack2bf(Oacc[mt][4 * g + 0] * inv, Oacc[mt][4 * g + 1] * inv);
            pk.y = pack2bf(Oacc[mt][4 * g + 2] * inv, Oacc[mt][4 * g + 3] * inv);
            *(uint2*)(O + base + (size_t)qrow * D_ + mt * 32 + 8 * g + 4 * half) = pk;
        }
}

extern "C" void kernel_launch(void* const* d_in, const int* in_sizes, int n_in,
                              void* d_out, int out_size, void* d_ws, size_t ws_size,
                              hipStream_t stream) {
    const float* x  = (const float*)d_in[0];
    const float* Wq = (const float*)d_in[1];
    const float* Wk = (const float*)d_in[2];
    const float* Wv = (const float*)d_in[3];
    const float* Wo = (const float*)d_in[4];
    float* out = (float*)d_out;

    char* ws = (char*)d_ws;
    const size_t MB = 1024 * 1024;
    // layout (72 MB total): Ob aliases xb (xb dead after QKV GEMM; stream-ordered)
    unsigned short* xb  = (unsigned short*)(ws);            // 16 MB
    unsigned short* wqb = (unsigned short*)(ws + 16 * MB);  // 2 MB
    unsigned short* wkb = (unsigned short*)(ws + 18 * MB);
    unsigned short* wvb = (unsigned short*)(ws + 20 * MB);
    unsigned short* wob = (unsigned short*)(ws + 22 * MB);
    unsigned short* Qb  = (unsigned short*)(ws + 24 * MB);  // 16 MB
    unsigned short* Kb  = (unsigned short*)(ws + 40 * MB);
    unsigned short* Vtb = (unsigned short*)(ws + 56 * MB);  // V transposed [B*H*DK, S]
    unsigned short* Ob  = (unsigned short*)(ws);            // alias xb

    CastAll ca;
    ca.x = x; ca.xd = xb;
    ca.w[0] = Wq; ca.w[1] = Wk; ca.w[2] = Wv; ca.w[3] = Wo;
    ca.wd[0] = wqb; ca.wd[1] = wkb; ca.wd[2] = wvb; ca.wd[3] = wob;
    // total float4 groups: 2M (x) + 4*256K (W) = 3,145,728 -> 12288 blocks
    cast_all_kernel<<<12288, 256, 0, stream>>>(ca);

    dim3 gq(D_ / 128, (B_ * S_) / 128, 3); // (8, 64, 3)
    gemm_bt<unsigned short, true><<<gq, 256, 0, stream>>>(
        xb, wqb, wkb, wvb, Qb, Kb, Vtb, B_ * S_, D_, D_);

    dim3 gf(S_ / 128, H_, B_); // (16, 16, 4)
    flash_attn<<<gf, 256, 0, stream>>>(Qb, Kb, Vtb, Ob);

    dim3 go(D_ / 128, (B_ * S_) / 128, 1);
    gemm_bt<float, false><<<go, 256, 0, stream>>>(
        Ob, wob, wob, wob, out, out, out, B_ * S_, D_, D_);
}